// Round 2
// baseline (672.975 us; speedup 1.0000x reference)
//
#include <hip/hip_runtime.h>

// Reaction-diffusion: c += (D*lap(c) + rho*c*(1-c)) * dt/steps, clip [0,1], 20 steps.
// 192^3 fp32. One kernel per step, ping-pong via workspace.
//
// Layout strategy:
//  - thread = one float4 x-strip; block = (48 x-threads, 4 y-rows) = 192 threads,
//    covering 4 contiguous rows (3 KB) -> perfectly coalesced 16B/lane loads.
//  - z-march: each block walks ZC z-planes keeping cm/cc/cp in registers, so c is
//    read once per element (as cp). y-neighbor rows re-hit L1 (loaded by the
//    adjacent thread the previous iteration).
//  - blockIdx.x = z-chunk (16), blockIdx.y = y-chunk (48): linear id = zc + 16*yc,
//    so y-neighbor chunks differ by 16 ≡ 0 mod 8 -> same XCD -> y-halo served by L2.

constexpr int W = 192, H = 192, DZ = 192;
constexpr int PLANE = W * H;
constexpr int NELEM = W * H * DZ;
constexpr int XT  = 48;          // x threads per block (float4 each: 48*4 = 192)
constexpr int YB  = 4;           // y rows per block
constexpr int ZCH = 16;          // z chunks
constexpr int ZC  = DZ / ZCH;    // 12 z-planes per chunk

__global__ __launch_bounds__(XT * YB) void rd_step(
    const float* __restrict__ c,
    const float* __restrict__ Dm,
    const float* __restrict__ rho,
    const float* __restrict__ dt,
    const int* __restrict__ steps,
    float* __restrict__ out)
{
    const int xt = threadIdx.x;              // 0..47
    const int yt = threadIdx.y;              // 0..3
    const int y  = blockIdx.y * YB + yt;     // 0..191
    const int x4 = xt * 4;                   // 0,4,...,188
    const int z0 = blockIdx.x * ZC;
    const int base = y * W + x4;

    const float delta_t = dt[0] / (float)steps[0];
    const float4 zero = make_float4(0.f, 0.f, 0.f, 0.f);

    // register z-pipeline: cm = c[z-1], cc = c[z], cp = c[z+1]
    float4 cm = (z0 > 0) ? *(const float4*)(c + (z0 - 1) * PLANE + base) : zero;
    float4 cc = *(const float4*)(c + z0 * PLANE + base);

    for (int z = z0; z < z0 + ZC; ++z) {
        const int zoff = z * PLANE + base;
        float4 cp = (z + 1 < DZ) ? *(const float4*)(c + zoff + PLANE) : zero;
        float4 ym = (y > 0)      ? *(const float4*)(c + zoff - W)     : zero;
        float4 yp = (y < H - 1)  ? *(const float4*)(c + zoff + W)     : zero;
        float xl  = (x4 > 0)     ? c[zoff - 1] : 0.f;
        float xr  = (x4 + 4 < W) ? c[zoff + 4] : 0.f;
        float4 Dv = *(const float4*)(Dm  + zoff);
        float4 rv = *(const float4*)(rho + zoff);

        float4 lap;
        lap.x = xl   + cc.y + ym.x + yp.x + cm.x + cp.x - 6.0f * cc.x;
        lap.y = cc.x + cc.z + ym.y + yp.y + cm.y + cp.y - 6.0f * cc.y;
        lap.z = cc.y + cc.w + ym.z + yp.z + cm.z + cp.z - 6.0f * cc.z;
        lap.w = cc.z + xr   + ym.w + yp.w + cm.w + cp.w - 6.0f * cc.w;

        float4 v;
        v.x = cc.x + (Dv.x * lap.x + rv.x * cc.x * (1.0f - cc.x)) * delta_t;
        v.y = cc.y + (Dv.y * lap.y + rv.y * cc.y * (1.0f - cc.y)) * delta_t;
        v.z = cc.z + (Dv.z * lap.z + rv.z * cc.z * (1.0f - cc.z)) * delta_t;
        v.w = cc.w + (Dv.w * lap.w + rv.w * cc.w * (1.0f - cc.w)) * delta_t;

        v.x = fminf(fmaxf(v.x, 0.f), 1.f);
        v.y = fminf(fmaxf(v.y, 0.f), 1.f);
        v.z = fminf(fmaxf(v.z, 0.f), 1.f);
        v.w = fminf(fmaxf(v.w, 0.f), 1.f);

        *(float4*)(out + zoff) = v;

        cm = cc;
        cc = cp;
    }
}

extern "C" void kernel_launch(void* const* d_in, const int* in_sizes, int n_in,
                              void* d_out, int out_size, void* d_ws, size_t ws_size,
                              hipStream_t stream) {
    const float* c_init = (const float*)d_in[0];
    const float* Dm     = (const float*)d_in[1];
    const float* rho    = (const float*)d_in[2];
    const float* dt     = (const float*)d_in[3];
    const int*   steps  = (const int*)d_in[4];   // value 20 (fixed by setup_inputs)

    float* bufA = (float*)d_ws;
    float* bufB = bufA + NELEM;
    float* outp = (float*)d_out;
    float* bufs[2] = { bufA, bufB };

    const int NSTEPS = 20;  // must match steps[0]; launch count is host-side

    dim3 block(XT, YB, 1);           // 192 threads
    dim3 grid(ZCH, H / YB, 1);       // 16 x 48 = 768 blocks

    const float* src = c_init;
    for (int s = 0; s < NSTEPS; ++s) {
        float* dst = (s == NSTEPS - 1) ? outp : bufs[s & 1];
        rd_step<<<grid, block, 0, stream>>>(src, Dm, rho, dt, steps, dst);
        src = dst;
    }
}

// Round 3
// 641.493 us; speedup vs baseline: 1.0491x; 1.0491x over previous
//
#include <hip/hip_runtime.h>

// Reaction-diffusion: c += (D*lap(c) + rho*c*(1-c)) * dt/steps, clip [0,1], 20 steps.
// 192^3 fp32. One kernel per step, ping-pong via workspace.
//
// R3: R2's float4 + register z-pipeline was latency-bound (768 blocks, 16.9% occ).
// Shrink z-march to ZC=4 -> 48x48 = 2304 blocks (6912 waves, ~27/CU) for latency
// hiding, keeping 1.5 c-loads/element (vs 3.0 without the march).
// Block id = zc + 48*yc: y-neighbor chunks differ by 48 = 0 mod 8 -> same XCD.

constexpr int W = 192, H = 192, DZ = 192;
constexpr int PLANE = W * H;
constexpr int NELEM = W * H * DZ;
constexpr int XT  = 48;          // x threads per block (float4 each: 48*4 = 192)
constexpr int YB  = 4;           // y rows per block
constexpr int ZC  = 4;           // z-planes per chunk (register pipeline depth)
constexpr int ZCH = DZ / ZC;     // 48 z chunks

__global__ __launch_bounds__(XT * YB) void rd_step(
    const float* __restrict__ c,
    const float* __restrict__ Dm,
    const float* __restrict__ rho,
    const float* __restrict__ dt,
    const int* __restrict__ steps,
    float* __restrict__ out)
{
    const int xt = threadIdx.x;              // 0..47
    const int yt = threadIdx.y;              // 0..3
    const int y  = blockIdx.y * YB + yt;     // 0..191
    const int x4 = xt * 4;                   // 0,4,...,188
    const int z0 = blockIdx.x * ZC;
    const int base = y * W + x4;

    const float delta_t = dt[0] / (float)steps[0];
    const float4 zero = make_float4(0.f, 0.f, 0.f, 0.f);

    // register z-pipeline: cm = c[z-1], cc = c[z], cp = c[z+1]
    float4 cm = (z0 > 0) ? *(const float4*)(c + (z0 - 1) * PLANE + base) : zero;
    float4 cc = *(const float4*)(c + z0 * PLANE + base);

    #pragma unroll
    for (int i = 0; i < ZC; ++i) {
        const int z = z0 + i;
        const int zoff = z * PLANE + base;
        float4 cp = (z + 1 < DZ) ? *(const float4*)(c + zoff + PLANE) : zero;
        float4 ym = (y > 0)      ? *(const float4*)(c + zoff - W)     : zero;
        float4 yp = (y < H - 1)  ? *(const float4*)(c + zoff + W)     : zero;
        float xl  = (x4 > 0)     ? c[zoff - 1] : 0.f;
        float xr  = (x4 + 4 < W) ? c[zoff + 4] : 0.f;
        float4 Dv = *(const float4*)(Dm  + zoff);
        float4 rv = *(const float4*)(rho + zoff);

        float4 lap;
        lap.x = xl   + cc.y + ym.x + yp.x + cm.x + cp.x - 6.0f * cc.x;
        lap.y = cc.x + cc.z + ym.y + yp.y + cm.y + cp.y - 6.0f * cc.y;
        lap.z = cc.y + cc.w + ym.z + yp.z + cm.z + cp.z - 6.0f * cc.z;
        lap.w = cc.z + xr   + ym.w + yp.w + cm.w + cp.w - 6.0f * cc.w;

        float4 v;
        v.x = cc.x + (Dv.x * lap.x + rv.x * cc.x * (1.0f - cc.x)) * delta_t;
        v.y = cc.y + (Dv.y * lap.y + rv.y * cc.y * (1.0f - cc.y)) * delta_t;
        v.z = cc.z + (Dv.z * lap.z + rv.z * cc.z * (1.0f - cc.z)) * delta_t;
        v.w = cc.w + (Dv.w * lap.w + rv.w * cc.w * (1.0f - cc.w)) * delta_t;

        v.x = fminf(fmaxf(v.x, 0.f), 1.f);
        v.y = fminf(fmaxf(v.y, 0.f), 1.f);
        v.z = fminf(fmaxf(v.z, 0.f), 1.f);
        v.w = fminf(fmaxf(v.w, 0.f), 1.f);

        *(float4*)(out + zoff) = v;

        cm = cc;
        cc = cp;
    }
}

extern "C" void kernel_launch(void* const* d_in, const int* in_sizes, int n_in,
                              void* d_out, int out_size, void* d_ws, size_t ws_size,
                              hipStream_t stream) {
    const float* c_init = (const float*)d_in[0];
    const float* Dm     = (const float*)d_in[1];
    const float* rho    = (const float*)d_in[2];
    const float* dt     = (const float*)d_in[3];
    const int*   steps  = (const int*)d_in[4];   // value 20 (fixed by setup_inputs)

    float* bufA = (float*)d_ws;
    float* bufB = bufA + NELEM;
    float* outp = (float*)d_out;
    float* bufs[2] = { bufA, bufB };

    const int NSTEPS = 20;  // must match steps[0]; launch count is host-side

    dim3 block(XT, YB, 1);           // 192 threads = 3 waves
    dim3 grid(ZCH, H / YB, 1);       // 48 x 48 = 2304 blocks

    const float* src = c_init;
    for (int s = 0; s < NSTEPS; ++s) {
        float* dst = (s == NSTEPS - 1) ? outp : bufs[s & 1];
        rd_step<<<grid, block, 0, stream>>>(src, Dm, rho, dt, steps, dst);
        src = dst;
    }
}